// Round 9
// baseline (119.391 us; speedup 1.0000x reference)
//
#include <hip/hip_runtime.h>

typedef __bf16 bf16x8 __attribute__((ext_vector_type(8)));
typedef float f32x4 __attribute__((ext_vector_type(4)));

__device__ __forceinline__ unsigned short f2bf(float x) {
  union { float f; unsigned int i; } u; u.f = x;
  return (unsigned short)((u.i + 0x7FFFu + ((u.i >> 16) & 1u)) >> 16);
}
__device__ __forceinline__ float bf2f(unsigned short b) {
  union { unsigned int i; float f; } u; u.i = ((unsigned int)b) << 16;
  return u.f;
}
__device__ __forceinline__ bf16x8 cvt8(float4 a, float4 b) {
  union { unsigned short u[8]; bf16x8 v; } r;
  r.u[0] = f2bf(a.x); r.u[1] = f2bf(a.y); r.u[2] = f2bf(a.z); r.u[3] = f2bf(a.w);
  r.u[4] = f2bf(b.x); r.u[5] = f2bf(b.y); r.u[6] = f2bf(b.z); r.u[7] = f2bf(b.w);
  return r.v;
}

// ---------------- pack W1 into MFMA B-fragment order (bf16) --------------
// B[k][n] = W1[c][jp*128 + k], n = nf*16+l15 (nf 0..23), c = n&127, jp = n>>7.
// frag storage idx = (kk*24 + nf)*64 + lane; elem j = B[kk*32+(l>>4)*8+j][n].
__global__ void pack_w1_kernel(const float* __restrict__ W1w, uint4* __restrict__ wp) {
  int fid = blockIdx.x * 256 + threadIdx.x;  // 0..6143
  int kk = fid / 1536;
  int rem = fid - kk * 1536;
  int nf = rem >> 6;
  int ln = rem & 63;
  int ng = nf * 16 + (ln & 15);
  int c = ng & 127;
  int jp = ng >> 7;
  int k0 = kk * 32 + (ln >> 4) * 8;
  const float* src = W1w + (size_t)c * 384 + jp * 128 + k0;
  float4 a = *(const float4*)src;
  float4 b = *(const float4*)(src + 4);
  union { unsigned short u[8]; uint4 v; } r;
  r.u[0] = f2bf(a.x); r.u[1] = f2bf(a.y); r.u[2] = f2bf(a.z); r.u[3] = f2bf(a.w);
  r.u[4] = f2bf(b.x); r.u[5] = f2bf(b.y); r.u[6] = f2bf(b.z); r.u[7] = f2bf(b.w);
  wp[fid] = r.v;
}

// ---------------- phase A: P = h @ W1^T  (dense, streaming) --------------
// Column-split (R8 geometry) + 2 tiles/block: block = (cs, tile2). cs picks
// 192 of 384 output cols -> 48 KB LDS stage -> 3 blocks/CU. After ONE stage,
// the block processes 2 adjacent 64-row tiles (128 rows) sequentially,
// halving staging traffic/barriers. acc[6] reused -> VGPR stays ~64.
__global__ __launch_bounds__(512, 6) void phaseA_kernel(
    const float* __restrict__ h, const uint4* __restrict__ wp,
    unsigned short* __restrict__ P, int Nn) {
  __shared__ uint4 wl[48 * 64];  // 48 KB
  const int tid = threadIdx.x;
  const int cs = blockIdx.x & 1;       // col slice: cols [cs*192, cs*192+192)
  const int tile2 = blockIdx.x >> 1;   // 128-row super-tile

  // stage this slice's fragments: LDS (kk*12+nfl)*64+ln <- wp[(kk*24+cs*12+nfl)*64+ln]
  for (int i = tid; i < 48 * 64; i += 512) {
    int fr = i >> 6;
    int ln = i & 63;
    int kk = fr / 12, nfl = fr - kk * 12;
    wl[i] = wp[(kk * 24 + cs * 12 + nfl) * 64 + ln];
  }
  __syncthreads();

  const int lane = tid & 63;
  const int wv = tid >> 6;       // 0..7
  const int rg = wv >> 1;        // 0..3
  const int cg = wv & 1;         // 0..1
  const int l15 = lane & 15;
  const int lg = lane >> 4;

#pragma unroll
  for (int tt = 0; tt < 2; tt++) {
    const int mb = (tile2 * 2 + tt) * 64 + rg * 16;
    if (mb >= Nn) break;
    int arow = mb + l15;
    if (arow >= Nn) arow = Nn - 1;
    const float* ap = h + (size_t)arow * 128 + lg * 8;

    f32x4 acc[6];
#pragma unroll
    for (int nf = 0; nf < 6; nf++) acc[nf] = (f32x4){0.f, 0.f, 0.f, 0.f};

#pragma unroll
    for (int kk = 0; kk < 4; kk++) {
      bf16x8 af = cvt8(*(const float4*)(ap + kk * 32), *(const float4*)(ap + kk * 32 + 4));
#pragma unroll
      for (int nf = 0; nf < 6; nf++) {
        bf16x8 bf = __builtin_bit_cast(bf16x8, wl[(kk * 12 + cg * 6 + nf) * 64 + lane]);
        acc[nf] = __builtin_amdgcn_mfma_f32_16x16x32_bf16(af, bf, acc[nf], 0, 0, 0);
      }
    }
    // D layout: row = lg*4 + r, col = cs*192 + cg*96 + nf*16 + l15
#pragma unroll
    for (int nf = 0; nf < 6; nf++) {
#pragma unroll
      for (int r = 0; r < 4; r++) {
        int row = mb + lg * 4 + r;
        if (row < Nn)
          P[(size_t)row * 384 + cs * 192 + cg * 96 + nf * 16 + l15] = f2bf(acc[nf][r]);
      }
    }
  }
}

// ---------------- phase B: gather-add + relu + layer2 --------------------
// 16 lanes per triplet; three 256B row fetches per triplet (16B/lane, contig).
// 5 triplets in flight per lane-group -> 15 outstanding 16B loads.
__global__ __launch_bounds__(256) void phaseB_kernel(
    const unsigned short* __restrict__ P, const int* __restrict__ trip,
    const float* __restrict__ b1, const float* __restrict__ W2w,
    const float* __restrict__ b2, float* __restrict__ out, int T) {
  constexpr int U = 5;
  const int gtid = blockIdx.x * 256 + threadIdx.x;
  const int g0 = gtid >> 4;
  const int c8 = threadIdx.x & 15;
  const int ng = (gridDim.x * 256) >> 4;
  const int c0 = c8 * 8;

  float4 b1a = *(const float4*)(b1 + c0), b1b = *(const float4*)(b1 + c0 + 4);
  float4 w0a = *(const float4*)(W2w + c0), w0b = *(const float4*)(W2w + c0 + 4);
  float4 w1a = *(const float4*)(W2w + 128 + c0), w1b = *(const float4*)(W2w + 128 + c0 + 4);
  const float bb0 = b2[0], bb1 = b2[1];
  float b1r[8] = {b1a.x, b1a.y, b1a.z, b1a.w, b1b.x, b1b.y, b1b.z, b1b.w};
  float w20[8] = {w0a.x, w0a.y, w0a.z, w0a.w, w0b.x, w0b.y, w0b.z, w0b.w};
  float w21[8] = {w1a.x, w1a.y, w1a.z, w1a.w, w1b.x, w1b.y, w1b.z, w1b.w};

  for (int t = g0; t < T; t += U * ng) {
    int tc[U];
    bool hv[U];
#pragma unroll
    for (int u = 0; u < U; u++) {
      int tt = t + u * ng;
      hv[u] = tt < T;
      tc[u] = hv[u] ? tt : t;
    }
    union { uint4 v; unsigned short u[8]; } va[U][3];
#pragma unroll
    for (int u = 0; u < U; u++) {
      int i0 = trip[3 * tc[u]], i1 = trip[3 * tc[u] + 1], i2 = trip[3 * tc[u] + 2];
      va[u][0].v = *((const uint4*)(P + (size_t)i0 * 384) + c8);
      va[u][1].v = *((const uint4*)(P + (size_t)i1 * 384 + 128) + c8);
      va[u][2].v = *((const uint4*)(P + (size_t)i2 * 384 + 256) + c8);
    }
    float p0[U], p1[U];
#pragma unroll
    for (int u = 0; u < U; u++) {
      p0[u] = 0.f; p1[u] = 0.f;
#pragma unroll
      for (int j = 0; j < 8; j++) {
        float s = bf2f(va[u][0].u[j]) + bf2f(va[u][1].u[j]) + bf2f(va[u][2].u[j]) + b1r[j];
        s = fmaxf(s, 0.f);
        p0[u] = fmaf(s, w20[j], p0[u]);
        p1[u] = fmaf(s, w21[j], p1[u]);
      }
    }
#pragma unroll
    for (int d = 1; d < 16; d <<= 1) {
#pragma unroll
      for (int u = 0; u < U; u++) {
        p0[u] += __shfl_xor(p0[u], d);
        p1[u] += __shfl_xor(p1[u], d);
      }
    }
    if (c8 == 0) {
#pragma unroll
      for (int u = 0; u < U; u++) {
        if (hv[u]) {
          float2 o;
          o.x = p0[u] + bb0;
          o.y = p1[u] + bb1;
          *(float2*)(out + (size_t)(t + u * ng) * 2) = o;
        }
      }
    }
  }
}

// ---------------- fallback (no/small ws): fused kernel -------------------
__global__ __launch_bounds__(512, 2) void fused_fallback(
    const float* __restrict__ Hsrc, const int* __restrict__ trip,
    const float* __restrict__ W1w, const float* __restrict__ b1,
    const float* __restrict__ W2w, const float* __restrict__ b2,
    float* __restrict__ out, int T) {
  extern __shared__ unsigned short w1p[];
  const int tid = threadIdx.x;
  for (int f = tid; f < 6144; f += 512) {
    int kk = f >> 9; int nf = (f >> 6) & 7; int ln = f & 63;
    int row = nf * 16 + (ln & 15); int k0 = kk * 32 + (ln >> 4) * 8;
    const float* src = W1w + row * 384 + k0;
    float4 a = *(const float4*)src; float4 b = *(const float4*)(src + 4);
    union { unsigned short u[8]; uint4 v; } r;
    r.u[0] = f2bf(a.x); r.u[1] = f2bf(a.y); r.u[2] = f2bf(a.z); r.u[3] = f2bf(a.w);
    r.u[4] = f2bf(b.x); r.u[5] = f2bf(b.y); r.u[6] = f2bf(b.z); r.u[7] = f2bf(b.w);
    *(uint4*)&w1p[f * 8] = r.v;
  }
  __syncthreads();
  const int lane = tid & 63, wv = tid >> 6, l15 = lane & 15, lg = lane >> 4;
  float b1r[8], w20[8], w21[8];
#pragma unroll
  for (int nf = 0; nf < 8; nf++) {
    int c = nf * 16 + l15;
    b1r[nf] = b1[c]; w20[nf] = W2w[c]; w21[nf] = W2w[128 + c];
  }
  const float bb0 = b2[0], bb1 = b2[1];
  const int ntiles = (T + 511) >> 9;
  for (int tile = blockIdx.x; tile < ntiles; tile += gridDim.x) {
    const int base = tile * 512 + wv * 64;
    f32x4 acc[4][8];
#pragma unroll
    for (int m = 0; m < 4; m++)
#pragma unroll
      for (int nf = 0; nf < 8; nf++) acc[m][nf] = (f32x4){0.f, 0.f, 0.f, 0.f};
    int off[4][3];
#pragma unroll
    for (int m = 0; m < 4; m++) {
      int row = base + m * 16 + l15;
      int rc = row < T ? row : T - 1;
      off[m][0] = trip[rc * 3]; off[m][1] = trip[rc * 3 + 1]; off[m][2] = trip[rc * 3 + 2];
    }
#pragma unroll
    for (int part = 0; part < 3; part++)
#pragma unroll
      for (int kq = 0; kq < 4; kq++) {
        const int kk = part * 4 + kq;
        bf16x8 af[4];
#pragma unroll
        for (int m = 0; m < 4; m++) {
          const float* p = Hsrc + ((size_t)off[m][part] << 7) + kq * 32 + lg * 8;
          af[m] = cvt8(*(const float4*)p, *(const float4*)(p + 4));
        }
#pragma unroll
        for (int nf = 0; nf < 8; nf++) {
          bf16x8 bf = __builtin_bit_cast(bf16x8,
              *(const uint4*)&w1p[(size_t)(kk * 512 + nf * 64 + lane) * 8]);
#pragma unroll
          for (int m = 0; m < 4; m++)
            acc[m][nf] = __builtin_amdgcn_mfma_f32_16x16x32_bf16(af[m], bf, acc[m][nf], 0, 0, 0);
        }
      }
#pragma unroll
    for (int m = 0; m < 4; m++) {
      float p0[4] = {0, 0, 0, 0}, p1[4] = {0, 0, 0, 0};
#pragma unroll
      for (int nf = 0; nf < 8; nf++)
#pragma unroll
        for (int r = 0; r < 4; r++) {
          float hv = fmaxf(acc[m][nf][r] + b1r[nf], 0.f);
          p0[r] = fmaf(hv, w20[nf], p0[r]);
          p1[r] = fmaf(hv, w21[nf], p1[r]);
        }
#pragma unroll
      for (int d = 1; d < 16; d <<= 1)
#pragma unroll
        for (int r = 0; r < 4; r++) {
          p0[r] += __shfl_xor(p0[r], d);
          p1[r] += __shfl_xor(p1[r], d);
        }
#pragma unroll
      for (int r = 0; r < 4; r++)
        if (l15 == r) {
          int row = base + m * 16 + lg * 4 + r;
          if (row < T) {
            float2 o; o.x = p0[r] + bb0; o.y = p1[r] + bb1;
            *(float2*)(out + (size_t)row * 2) = o;
          }
        }
    }
  }
}

extern "C" void kernel_launch(void* const* d_in, const int* in_sizes, int n_in,
                              void* d_out, int out_size, void* d_ws, size_t ws_size,
                              hipStream_t stream) {
  const float* h = (const float*)d_in[0];
  const int* trip = (const int*)d_in[1];
  const float* W1w = (const float*)d_in[2];
  const float* b1 = (const float*)d_in[3];
  const float* W2w = (const float*)d_in[4];
  const float* b2 = (const float*)d_in[5];
  float* out = (float*)d_out;

  const int Nn = in_sizes[0] / 128;
  const int T = in_sizes[1] / 3;
  const size_t pbytes = (size_t)Nn * 384 * 2;     // bf16 P table
  const size_t need = pbytes + 6144 * 16;         // + packed W1

  if (ws_size >= need) {
    unsigned short* P = (unsigned short*)d_ws;
    uint4* wp = (uint4*)((char*)d_ws + pbytes);
    pack_w1_kernel<<<24, 256, 0, stream>>>(W1w, wp);
    const int ntiles2 = (Nn + 127) >> 7;
    phaseA_kernel<<<ntiles2 * 2, 512, 0, stream>>>(h, wp, P, Nn);
    phaseB_kernel<<<2048, 256, 0, stream>>>(P, trip, b1, W2w, b2, out, T);
  } else {
    fused_fallback<<<256, 512, 6144 * 16, stream>>>(h, trip, W1w, b1, W2w, b2, out, T);
  }
}

// Round 10
// 101.708 us; speedup vs baseline: 1.1739x; 1.1739x over previous
//
#include <hip/hip_runtime.h>

typedef __bf16 bf16x8 __attribute__((ext_vector_type(8)));
typedef float f32x4 __attribute__((ext_vector_type(4)));

__device__ __forceinline__ unsigned short f2bf(float x) {
  union { float f; unsigned int i; } u; u.f = x;
  return (unsigned short)((u.i + 0x7FFFu + ((u.i >> 16) & 1u)) >> 16);
}
__device__ __forceinline__ float bf2f(unsigned short b) {
  union { unsigned int i; float f; } u; u.i = ((unsigned int)b) << 16;
  return u.f;
}
__device__ __forceinline__ bf16x8 cvt8(float4 a, float4 b) {
  union { unsigned short u[8]; bf16x8 v; } r;
  r.u[0] = f2bf(a.x); r.u[1] = f2bf(a.y); r.u[2] = f2bf(a.z); r.u[3] = f2bf(a.w);
  r.u[4] = f2bf(b.x); r.u[5] = f2bf(b.y); r.u[6] = f2bf(b.z); r.u[7] = f2bf(b.w);
  return r.v;
}

// ---------------- pack W1 into MFMA B-fragment order (bf16) --------------
// B[k][n] = W1[c][jp*128 + k], n = nf*16+l15 (nf 0..23), c = n&127, jp = n>>7.
// frag storage idx = (kk*24 + nf)*64 + lane; elem j = B[kk*32+(l>>4)*8+j][n].
__global__ void pack_w1_kernel(const float* __restrict__ W1w, uint4* __restrict__ wp) {
  int fid = blockIdx.x * 256 + threadIdx.x;  // 0..6143
  int kk = fid / 1536;
  int rem = fid - kk * 1536;
  int nf = rem >> 6;
  int ln = rem & 63;
  int ng = nf * 16 + (ln & 15);
  int c = ng & 127;
  int jp = ng >> 7;
  int k0 = kk * 32 + (ln >> 4) * 8;
  const float* src = W1w + (size_t)c * 384 + jp * 128 + k0;
  float4 a = *(const float4*)src;
  float4 b = *(const float4*)(src + 4);
  union { unsigned short u[8]; uint4 v; } r;
  r.u[0] = f2bf(a.x); r.u[1] = f2bf(a.y); r.u[2] = f2bf(a.z); r.u[3] = f2bf(a.w);
  r.u[4] = f2bf(b.x); r.u[5] = f2bf(b.y); r.u[6] = f2bf(b.z); r.u[7] = f2bf(b.w);
  wp[fid] = r.v;
}

// ---------------- phase A: P = h @ W1^T  (dense, streaming) --------------
// R8 geometry (col-split, 48 KB LDS, 3 blocks/CU, 1 tile/block) plus:
//  (a) XCD pairing: (cs=0,cs=1) of a tile run consecutively on the same XCD
//      so the second slice's h reads hit that XCD's L2.
//  (b) full-line P writes: acc -> LDS (reusing the B-frag buffer after a
//      barrier, padded stride 200 u16) -> coalesced uint4 stores, so each
//      128B line of P is produced by one contiguous wave store stream.
#define OT_STRIDE 200  // u16; 400 B/row: 16B-aligned, breaks 32-bank alignment
__global__ __launch_bounds__(512, 6) void phaseA_kernel(
    const float* __restrict__ h, const uint4* __restrict__ wp,
    unsigned short* __restrict__ P, int Nn, int ntiles) {
  __shared__ uint4 wl[48 * 64];  // 48 KB: B frags, later reused as out-tile
  const int tid = threadIdx.x;
  const int b = blockIdx.x;
  const int xcd = b & 7;
  const int j = b >> 3;
  const int cs = j & 1;                  // col slice: [cs*192, cs*192+192)
  const int tile = (j >> 1) * 8 + xcd;   // 64-row tile
  if (tile >= ntiles) return;

  // stage this slice's fragments: LDS (kk*12+nfl)*64+ln <- wp[(kk*24+cs*12+nfl)*64+ln]
  for (int i = tid; i < 48 * 64; i += 512) {
    int fr = i >> 6;
    int ln = i & 63;
    int kk = fr / 12, nfl = fr - kk * 12;
    wl[i] = wp[(kk * 24 + cs * 12 + nfl) * 64 + ln];
  }
  __syncthreads();

  const int lane = tid & 63;
  const int wv = tid >> 6;       // 0..7
  const int rg = wv >> 1;        // 0..3
  const int cg = wv & 1;         // 0..1
  const int l15 = lane & 15;
  const int lg = lane >> 4;

  const int mb = tile * 64 + rg * 16;
  int arow = mb + l15;
  if (arow >= Nn) arow = Nn - 1;
  const float* ap = h + (size_t)arow * 128 + lg * 8;

  f32x4 acc[6];
#pragma unroll
  for (int nf = 0; nf < 6; nf++) acc[nf] = (f32x4){0.f, 0.f, 0.f, 0.f};

#pragma unroll
  for (int kk = 0; kk < 4; kk++) {
    bf16x8 af = cvt8(*(const float4*)(ap + kk * 32), *(const float4*)(ap + kk * 32 + 4));
#pragma unroll
    for (int nf = 0; nf < 6; nf++) {
      bf16x8 bf = __builtin_bit_cast(bf16x8, wl[(kk * 12 + cg * 6 + nf) * 64 + lane]);
      acc[nf] = __builtin_amdgcn_mfma_f32_16x16x32_bf16(af, bf, acc[nf], 0, 0, 0);
    }
  }

  // ---- acc -> LDS (B frags dead now). D layout: row = rg*16+lg*4+r,
  // within-slice col = cg*96 + nf*16 + l15.
  __syncthreads();
  unsigned short* ot = (unsigned short*)wl;  // [64][OT_STRIDE]
#pragma unroll
  for (int nf = 0; nf < 6; nf++)
#pragma unroll
    for (int r = 0; r < 4; r++)
      ot[(rg * 16 + lg * 4 + r) * OT_STRIDE + cg * 96 + nf * 16 + l15] =
          f2bf(acc[nf][r]);
  __syncthreads();

  // ---- coalesced stream-out: 64 rows x 24 uint4 (full 384B slice per row)
  const int r0 = tile * 64;
  if (r0 + 64 <= Nn) {
#pragma unroll
    for (int pass = 0; pass < 3; pass++) {
      int i = pass * 512 + tid;           // 0..1535 = 64*24
      int row = i / 24, c = i - row * 24;
      uint4 v = *(const uint4*)&ot[row * OT_STRIDE + c * 8];
      *(uint4*)(P + (size_t)(r0 + row) * 384 + cs * 192 + c * 8) = v;
    }
  } else {
    for (int i = tid; i < 64 * 24; i += 512) {
      int row = i / 24, c = i - row * 24;
      if (r0 + row < Nn) {
        uint4 v = *(const uint4*)&ot[row * OT_STRIDE + c * 8];
        *(uint4*)(P + (size_t)(r0 + row) * 384 + cs * 192 + c * 8) = v;
      }
    }
  }
}

// ---------------- phase B: gather-add + relu + layer2 --------------------
// 16 lanes per triplet; three 256B row fetches per triplet (16B/lane, contig).
// 5 triplets in flight per lane-group -> 15 outstanding 16B loads.
__global__ __launch_bounds__(256) void phaseB_kernel(
    const unsigned short* __restrict__ P, const int* __restrict__ trip,
    const float* __restrict__ b1, const float* __restrict__ W2w,
    const float* __restrict__ b2, float* __restrict__ out, int T) {
  constexpr int U = 5;
  const int gtid = blockIdx.x * 256 + threadIdx.x;
  const int g0 = gtid >> 4;
  const int c8 = threadIdx.x & 15;
  const int ng = (gridDim.x * 256) >> 4;
  const int c0 = c8 * 8;

  float4 b1a = *(const float4*)(b1 + c0), b1b = *(const float4*)(b1 + c0 + 4);
  float4 w0a = *(const float4*)(W2w + c0), w0b = *(const float4*)(W2w + c0 + 4);
  float4 w1a = *(const float4*)(W2w + 128 + c0), w1b = *(const float4*)(W2w + 128 + c0 + 4);
  const float bb0 = b2[0], bb1 = b2[1];
  float b1r[8] = {b1a.x, b1a.y, b1a.z, b1a.w, b1b.x, b1b.y, b1b.z, b1b.w};
  float w20[8] = {w0a.x, w0a.y, w0a.z, w0a.w, w0b.x, w0b.y, w0b.z, w0b.w};
  float w21[8] = {w1a.x, w1a.y, w1a.z, w1a.w, w1b.x, w1b.y, w1b.z, w1b.w};

  for (int t = g0; t < T; t += U * ng) {
    int tc[U];
    bool hv[U];
#pragma unroll
    for (int u = 0; u < U; u++) {
      int tt = t + u * ng;
      hv[u] = tt < T;
      tc[u] = hv[u] ? tt : t;
    }
    union { uint4 v; unsigned short u[8]; } va[U][3];
#pragma unroll
    for (int u = 0; u < U; u++) {
      int i0 = trip[3 * tc[u]], i1 = trip[3 * tc[u] + 1], i2 = trip[3 * tc[u] + 2];
      va[u][0].v = *((const uint4*)(P + (size_t)i0 * 384) + c8);
      va[u][1].v = *((const uint4*)(P + (size_t)i1 * 384 + 128) + c8);
      va[u][2].v = *((const uint4*)(P + (size_t)i2 * 384 + 256) + c8);
    }
    float p0[U], p1[U];
#pragma unroll
    for (int u = 0; u < U; u++) {
      p0[u] = 0.f; p1[u] = 0.f;
#pragma unroll
      for (int j = 0; j < 8; j++) {
        float s = bf2f(va[u][0].u[j]) + bf2f(va[u][1].u[j]) + bf2f(va[u][2].u[j]) + b1r[j];
        s = fmaxf(s, 0.f);
        p0[u] = fmaf(s, w20[j], p0[u]);
        p1[u] = fmaf(s, w21[j], p1[u]);
      }
    }
#pragma unroll
    for (int d = 1; d < 16; d <<= 1) {
#pragma unroll
      for (int u = 0; u < U; u++) {
        p0[u] += __shfl_xor(p0[u], d);
        p1[u] += __shfl_xor(p1[u], d);
      }
    }
    if (c8 == 0) {
#pragma unroll
      for (int u = 0; u < U; u++) {
        if (hv[u]) {
          float2 o;
          o.x = p0[u] + bb0;
          o.y = p1[u] + bb1;
          *(float2*)(out + (size_t)(t + u * ng) * 2) = o;
        }
      }
    }
  }
}

// ---------------- fallback (no/small ws): fused kernel -------------------
__global__ __launch_bounds__(512, 2) void fused_fallback(
    const float* __restrict__ Hsrc, const int* __restrict__ trip,
    const float* __restrict__ W1w, const float* __restrict__ b1,
    const float* __restrict__ W2w, const float* __restrict__ b2,
    float* __restrict__ out, int T) {
  extern __shared__ unsigned short w1p[];
  const int tid = threadIdx.x;
  for (int f = tid; f < 6144; f += 512) {
    int kk = f >> 9; int nf = (f >> 6) & 7; int ln = f & 63;
    int row = nf * 16 + (ln & 15); int k0 = kk * 32 + (ln >> 4) * 8;
    const float* src = W1w + row * 384 + k0;
    float4 a = *(const float4*)src; float4 b = *(const float4*)(src + 4);
    union { unsigned short u[8]; uint4 v; } r;
    r.u[0] = f2bf(a.x); r.u[1] = f2bf(a.y); r.u[2] = f2bf(a.z); r.u[3] = f2bf(a.w);
    r.u[4] = f2bf(b.x); r.u[5] = f2bf(b.y); r.u[6] = f2bf(b.z); r.u[7] = f2bf(b.w);
    *(uint4*)&w1p[f * 8] = r.v;
  }
  __syncthreads();
  const int lane = tid & 63, wv = tid >> 6, l15 = lane & 15, lg = lane >> 4;
  float b1r[8], w20[8], w21[8];
#pragma unroll
  for (int nf = 0; nf < 8; nf++) {
    int c = nf * 16 + l15;
    b1r[nf] = b1[c]; w20[nf] = W2w[c]; w21[nf] = W2w[128 + c];
  }
  const float bb0 = b2[0], bb1 = b2[1];
  const int ntiles = (T + 511) >> 9;
  for (int tile = blockIdx.x; tile < ntiles; tile += gridDim.x) {
    const int base = tile * 512 + wv * 64;
    f32x4 acc[4][8];
#pragma unroll
    for (int m = 0; m < 4; m++)
#pragma unroll
      for (int nf = 0; nf < 8; nf++) acc[m][nf] = (f32x4){0.f, 0.f, 0.f, 0.f};
    int off[4][3];
#pragma unroll
    for (int m = 0; m < 4; m++) {
      int row = base + m * 16 + l15;
      int rc = row < T ? row : T - 1;
      off[m][0] = trip[rc * 3]; off[m][1] = trip[rc * 3 + 1]; off[m][2] = trip[rc * 3 + 2];
    }
#pragma unroll
    for (int part = 0; part < 3; part++)
#pragma unroll
      for (int kq = 0; kq < 4; kq++) {
        const int kk = part * 4 + kq;
        bf16x8 af[4];
#pragma unroll
        for (int m = 0; m < 4; m++) {
          const float* p = Hsrc + ((size_t)off[m][part] << 7) + kq * 32 + lg * 8;
          af[m] = cvt8(*(const float4*)p, *(const float4*)(p + 4));
        }
#pragma unroll
        for (int nf = 0; nf < 8; nf++) {
          bf16x8 bf = __builtin_bit_cast(bf16x8,
              *(const uint4*)&w1p[(size_t)(kk * 512 + nf * 64 + lane) * 8]);
#pragma unroll
          for (int m = 0; m < 4; m++)
            acc[m][nf] = __builtin_amdgcn_mfma_f32_16x16x32_bf16(af[m], bf, acc[m][nf], 0, 0, 0);
        }
      }
#pragma unroll
    for (int m = 0; m < 4; m++) {
      float p0[4] = {0, 0, 0, 0}, p1[4] = {0, 0, 0, 0};
#pragma unroll
      for (int nf = 0; nf < 8; nf++)
#pragma unroll
        for (int r = 0; r < 4; r++) {
          float hv = fmaxf(acc[m][nf][r] + b1r[nf], 0.f);
          p0[r] = fmaf(hv, w20[nf], p0[r]);
          p1[r] = fmaf(hv, w21[nf], p1[r]);
        }
#pragma unroll
      for (int d = 1; d < 16; d <<= 1)
#pragma unroll
        for (int r = 0; r < 4; r++) {
          p0[r] += __shfl_xor(p0[r], d);
          p1[r] += __shfl_xor(p1[r], d);
        }
#pragma unroll
      for (int r = 0; r < 4; r++)
        if (l15 == r) {
          int row = base + m * 16 + lg * 4 + r;
          if (row < T) {
            float2 o; o.x = p0[r] + bb0; o.y = p1[r] + bb1;
            *(float2*)(out + (size_t)row * 2) = o;
          }
        }
    }
  }
}

extern "C" void kernel_launch(void* const* d_in, const int* in_sizes, int n_in,
                              void* d_out, int out_size, void* d_ws, size_t ws_size,
                              hipStream_t stream) {
  const float* h = (const float*)d_in[0];
  const int* trip = (const int*)d_in[1];
  const float* W1w = (const float*)d_in[2];
  const float* b1 = (const float*)d_in[3];
  const float* W2w = (const float*)d_in[4];
  const float* b2 = (const float*)d_in[5];
  float* out = (float*)d_out;

  const int Nn = in_sizes[0] / 128;
  const int T = in_sizes[1] / 3;
  const size_t pbytes = (size_t)Nn * 384 * 2;     // bf16 P table
  const size_t need = pbytes + 6144 * 16;         // + packed W1

  if (ws_size >= need) {
    unsigned short* P = (unsigned short*)d_ws;
    uint4* wp = (uint4*)((char*)d_ws + pbytes);
    pack_w1_kernel<<<24, 256, 0, stream>>>(W1w, wp);
    const int ntiles = (Nn + 63) >> 6;
    const int ntp = ((ntiles + 7) >> 3) << 3;   // pad to multiple of 8 (XCD pairing)
    phaseA_kernel<<<ntp * 2, 512, 0, stream>>>(h, wp, P, Nn, ntiles);
    phaseB_kernel<<<2048, 256, 0, stream>>>(P, trip, b1, W2w, b2, out, T);
  } else {
    fused_fallback<<<256, 512, 6144 * 16, stream>>>(h, trip, W1w, b1, W2w, b2, out, T);
  }
}